// Round 1
// baseline (5716.144 us; speedup 1.0000x reference)
//
#include <hip/hip_runtime.h>
#include <hip/hip_bf16.h>
#include <math.h>

#define N_NODES 65536
#define N_EDGES 524288
#define N_GRAPHS 1024
#define NPG 64
#define FD 78

// ---------------- GEMM: C = A[M,K] @ B[K,N] (+bias) (+relu), row-major, ldc ----------------
// 64x64 tile, 256 threads, 4x4 per thread, f32.
#define TM 64
#define TN 64
#define TK 16

__global__ __launch_bounds__(256) void gemm_bias_act(
    const float* __restrict__ A, const float* __restrict__ B,
    const float* __restrict__ bias, float* __restrict__ C,
    int M, int N, int K, int ldc, int relu)
{
    __shared__ float As[TK][TM + 1];
    __shared__ float Bs[TK][TN + 1];
    int tid = threadIdx.x;
    int bm = blockIdx.y * TM;
    int bn = blockIdx.x * TN;
    int tr = tid >> 4;          // 0..15
    int tc = tid & 15;          // 0..15
    float acc[4][4] = {};

    for (int k0 = 0; k0 < K; k0 += TK) {
        // load A tile: 64 rows x 16 k  (M is always a multiple of 64 here)
        #pragma unroll
        for (int i = tid; i < TM * TK; i += 256) {
            int r = i >> 4, c = i & 15;
            float v = 0.f;
            if (k0 + c < K) v = A[(size_t)(bm + r) * K + (k0 + c)];
            As[c][r] = v;
        }
        // load B tile: 16 k x 64 cols
        #pragma unroll
        for (int i = tid; i < TK * TN; i += 256) {
            int r = i >> 6, c = i & 63;
            float v = 0.f;
            if ((k0 + r) < K && (bn + c) < N) v = B[(size_t)(k0 + r) * N + (bn + c)];
            Bs[r][c] = v;
        }
        __syncthreads();
        #pragma unroll
        for (int kk = 0; kk < TK; ++kk) {
            float a[4], b[4];
            #pragma unroll
            for (int i = 0; i < 4; ++i) a[i] = As[kk][tr + i * 16];
            #pragma unroll
            for (int j = 0; j < 4; ++j) b[j] = Bs[kk][tc + j * 16];
            #pragma unroll
            for (int i = 0; i < 4; ++i)
                #pragma unroll
                for (int j = 0; j < 4; ++j)
                    acc[i][j] = fmaf(a[i], b[j], acc[i][j]);
        }
        __syncthreads();
    }
    #pragma unroll
    for (int i = 0; i < 4; ++i) {
        int r = bm + tr + i * 16;
        if (r >= M) continue;
        #pragma unroll
        for (int j = 0; j < 4; ++j) {
            int c = bn + tc + j * 16;
            if (c >= N) continue;
            float v = acc[i][j];
            if (bias) v += bias[c];
            if (relu) v = fmaxf(v, 0.f);
            C[(size_t)r * ldc + c] = v;
        }
    }
}

// ---------------- graph helper kernels ----------------
__global__ void count_deg(const int* __restrict__ dst, int* __restrict__ cnt, int E) {
    int t = blockIdx.x * blockDim.x + threadIdx.x;
    if (t < E) atomicAdd(&cnt[dst[t]], 1);
}

__global__ void make_dinv(const int* __restrict__ cnt, float* __restrict__ dinv, int n) {
    int t = blockIdx.x * blockDim.x + threadIdx.x;
    if (t < n) dinv[t] = rsqrtf((float)cnt[t] + 1.0f);
}

__global__ void make_coef(const int* __restrict__ src, const int* __restrict__ dst,
                          const float* __restrict__ dinv, float* __restrict__ coef, int E) {
    int t = blockIdx.x * blockDim.x + threadIdx.x;
    if (t < E) coef[t] = dinv[src[t]] * dinv[dst[t]];
}

// agg[i,f] = h[i,f] * dinv[i]^2   (self-loop term, also serves as the init)
__global__ void selfloop_init(const float* __restrict__ h, const float* __restrict__ dinv,
                              float* __restrict__ agg, int total, int F) {
    int t = blockIdx.x * blockDim.x + threadIdx.x;
    if (t < total) {
        int i = t / F;
        float d = dinv[i];
        agg[t] = h[t] * d * d;
    }
}

// agg[dst] += coef[e] * h[src]   one thread = one edge x two features
__global__ void edge_agg(const float* __restrict__ h, const int* __restrict__ src,
                         const int* __restrict__ dst, const float* __restrict__ coef,
                         float* __restrict__ agg, int E, int F2) {
    int t = blockIdx.x * blockDim.x + threadIdx.x;
    int total = E * F2;
    if (t >= total) return;
    int e = t / F2;
    int f2 = t - e * F2;
    int s = src[e], d = dst[e];
    float c = coef[e];
    const float2 hv = *(const float2*)(h + (size_t)s * (F2 * 2) + 2 * f2);
    float* ap = agg + (size_t)d * (F2 * 2) + 2 * f2;
    atomicAdd(ap + 0, hv.x * c);
    atomicAdd(ap + 1, hv.y * c);
}

__global__ void bias_relu(const float* __restrict__ agg, const float* __restrict__ b,
                          float* __restrict__ y, int total, int F) {
    int t = blockIdx.x * blockDim.x + threadIdx.x;
    if (t < total) {
        int f = t % F;
        y[t] = fmaxf(agg[t] + b[f], 0.f);
    }
}

// global max pool: 64 contiguous nodes per graph
__global__ void pool_max(const float* __restrict__ y, float* __restrict__ out, int F) {
    int g = blockIdx.x;
    for (int f = threadIdx.x; f < F; f += blockDim.x) {
        float m = -INFINITY;
        const float* p = y + (size_t)g * NPG * F + f;
        #pragma unroll 4
        for (int n = 0; n < NPG; ++n) m = fmaxf(m, p[(size_t)n * F]);
        out[(size_t)g * F + f] = m;
    }
}

// ---------------- host side ----------------
static inline void gemm_launch(const float* A, const float* B, const float* bias, float* C,
                               int M, int N, int K, int ldc, int relu, hipStream_t s) {
    dim3 grid((N + TN - 1) / TN, (M + TM - 1) / TM);
    gemm_bias_act<<<grid, 256, 0, s>>>(A, B, bias, C, M, N, K, ldc, relu);
}

extern "C" void kernel_launch(void* const* d_in, const int* in_sizes, int n_in,
                              void* d_out, int out_size, void* d_ws, size_t ws_size,
                              hipStream_t stream) {
    (void)in_sizes; (void)n_in; (void)out_size; (void)ws_size;

    const float* x1     = (const float*)d_in[0];
    const int*   ei1    = (const int*)d_in[1];
    const float* x2     = (const float*)d_in[3];
    const int*   ei2    = (const int*)d_in[4];
    const float* target = (const float*)d_in[6];

    // per-branch params start at 7 (d1) and 17 (d2)
    const float* xt_w  = (const float*)d_in[27];
    const float* xt_b  = (const float*)d_in[28];
    const float* fc1_w = (const float*)d_in[29];
    const float* fc1_b = (const float*)d_in[30];
    const float* fc2_w = (const float*)d_in[31];
    const float* fc2_b = (const float*)d_in[32];
    const float* out_w = (const float*)d_in[33];
    const float* out_b = (const float*)d_in[34];

    char* ws = (char*)d_ws;
    // layout (bytes)
    float* buf1 = (float*)(ws + 0);                      // 65536*312*4 = 81,788,928
    float* buf2 = (float*)(ws + 81788928);               // 81,788,928
    int*   cnt  = (int*)  (ws + 163577856);              // 262,144
    float* dinv = (float*)(ws + 163840000);              // 262,144
    float* coef = (float*)(ws + 164102144);              // 2,097,152
    float* xc   = (float*)(ws + 166199296);              // 1024*256*4 = 1,048,576
    float* xc1  = (float*)(ws + 167247872);              // 1024*128*4 = 524,288
    float* xc2  = (float*)(ws + 167772160);              // 1024*32*4  = 131,072
    // aliases inside buf2 once conv work there is done:
    float* pooled = buf2;                                // 1024*312*4 = 1,277,952
    float* fc_out = (float*)((char*)buf2 + 2097152);     // 1024*1024*4 = 4 MB

    const int E = N_EDGES;
    const int EB = (E + 255) / 256;
    const int NB = (N_NODES + 255) / 256;

    for (int br = 0; br < 2; ++br) {
        const float* x   = br == 0 ? x1 : x2;
        const int*   ei  = br == 0 ? ei1 : ei2;
        const int*   src = ei;
        const int*   dst = ei + E;
        int base = 7 + br * 10;
        const float* w1    = (const float*)d_in[base + 0];
        const float* b1    = (const float*)d_in[base + 1];
        const float* w2    = (const float*)d_in[base + 2];
        const float* b2    = (const float*)d_in[base + 3];
        const float* w3    = (const float*)d_in[base + 4];
        const float* b3    = (const float*)d_in[base + 5];
        const float* bfc1w = (const float*)d_in[base + 6];
        const float* bfc1b = (const float*)d_in[base + 7];
        const float* bfc2w = (const float*)d_in[base + 8];
        const float* bfc2b = (const float*)d_in[base + 9];

        // degree -> dinv -> coef (same for all 3 convs of this branch)
        hipMemsetAsync(cnt, 0, N_NODES * sizeof(int), stream);
        count_deg<<<EB, 256, 0, stream>>>(dst, cnt, E);
        make_dinv<<<NB, 256, 0, stream>>>(cnt, dinv, N_NODES);
        make_coef<<<EB, 256, 0, stream>>>(src, dst, dinv, coef, E);

        // conv helper inline: x_in -> y   (h in bufH, agg in bufA, y overwrites bufH)
        struct ConvSpec { const float* xin; float* h; float* agg; const float* w; const float* b; int Fin; int Fout; };
        ConvSpec convs[3] = {
            { x,    buf1, buf2, w1, b1, FD,      FD      },
            { buf1, buf2, buf1, w2, b2, FD,      FD * 2  },
            { buf2, buf1, buf2, w3, b3, FD * 2,  FD * 4  },
        };
        for (int ci = 0; ci < 3; ++ci) {
            ConvSpec& cs = convs[ci];
            int total = N_NODES * cs.Fout;
            int TBLK = (total + 255) / 256;
            gemm_launch(cs.xin, cs.w, nullptr, cs.h, N_NODES, cs.Fout, cs.Fin, cs.Fout, 0, stream);
            selfloop_init<<<TBLK, 256, 0, stream>>>(cs.h, dinv, cs.agg, total, cs.Fout);
            int F2 = cs.Fout / 2;
            long etotal = (long)E * F2;
            edge_agg<<<(int)((etotal + 255) / 256), 256, 0, stream>>>(cs.h, src, dst, coef, cs.agg, E, F2);
            bias_relu<<<TBLK, 256, 0, stream>>>(cs.agg, cs.b, cs.h, total, cs.Fout);
        }
        // y3 is now in buf1 (conv3: agg=buf2, y written to h=buf1)

        // pool: buf1 [65536,312] -> pooled (alias at buf2) [1024,312]
        pool_max<<<N_GRAPHS, 256, 0, stream>>>(buf1, pooled, FD * 4);
        // fc1: [1024,312] @ [312,1024] + b, relu -> fc_out
        gemm_launch(pooled, bfc1w, bfc1b, fc_out, N_GRAPHS, 1024, FD * 4, 1024, 1, stream);
        // fc2: [1024,1024] @ [1024,64] + b -> xc columns [br*64 .. br*64+64)
        gemm_launch(fc_out, bfc2w, bfc2b, xc + br * 64, N_GRAPHS, 64, 1024, 256, 0, stream);
    }

    // xt: [1024,1000] @ [1000,128] + b -> xc columns [128..256)
    gemm_launch(target, xt_w, xt_b, xc + 128, N_GRAPHS, 128, 1000, 256, 0, stream);
    // head
    gemm_launch(xc,  fc1_w, fc1_b, xc1, N_GRAPHS, 128, 256, 128, 1, stream);
    gemm_launch(xc1, fc2_w, fc2_b, xc2, N_GRAPHS, 32, 128, 32, 1, stream);
    gemm_launch(xc2, out_w, out_b, (float*)d_out, N_GRAPHS, 1, 32, 1, 0, stream);
}

// Round 2
// 1829.515 us; speedup vs baseline: 3.1244x; 3.1244x over previous
//
#include <hip/hip_runtime.h>
#include <hip/hip_bf16.h>
#include <math.h>

#define N_NODES 65536
#define N_EDGES 524288
#define N_GRAPHS 1024
#define NPG 64
#define FD 78

// ---------------- GEMM: C = A[M,K] @ B[K,N] (+bias) (+relu), row-major, ldc ----------------
// 64x64 tile, 256 threads, 4x4 per thread, f32.
#define TM 64
#define TN 64
#define TK 16

__global__ __launch_bounds__(256) void gemm_bias_act(
    const float* __restrict__ A, const float* __restrict__ B,
    const float* __restrict__ bias, float* __restrict__ C,
    int M, int N, int K, int ldc, int relu)
{
    __shared__ float As[TK][TM + 1];
    __shared__ float Bs[TK][TN + 1];
    int tid = threadIdx.x;
    int bm = blockIdx.y * TM;
    int bn = blockIdx.x * TN;
    int tr = tid >> 4;          // 0..15
    int tc = tid & 15;          // 0..15
    float acc[4][4] = {};

    for (int k0 = 0; k0 < K; k0 += TK) {
        #pragma unroll
        for (int i = tid; i < TM * TK; i += 256) {
            int r = i >> 4, c = i & 15;
            float v = 0.f;
            if (k0 + c < K) v = A[(size_t)(bm + r) * K + (k0 + c)];
            As[c][r] = v;
        }
        #pragma unroll
        for (int i = tid; i < TK * TN; i += 256) {
            int r = i >> 6, c = i & 63;
            float v = 0.f;
            if ((k0 + r) < K && (bn + c) < N) v = B[(size_t)(k0 + r) * N + (bn + c)];
            Bs[r][c] = v;
        }
        __syncthreads();
        #pragma unroll
        for (int kk = 0; kk < TK; ++kk) {
            float a[4], b[4];
            #pragma unroll
            for (int i = 0; i < 4; ++i) a[i] = As[kk][tr + i * 16];
            #pragma unroll
            for (int j = 0; j < 4; ++j) b[j] = Bs[kk][tc + j * 16];
            #pragma unroll
            for (int i = 0; i < 4; ++i)
                #pragma unroll
                for (int j = 0; j < 4; ++j)
                    acc[i][j] = fmaf(a[i], b[j], acc[i][j]);
        }
        __syncthreads();
    }
    #pragma unroll
    for (int i = 0; i < 4; ++i) {
        int r = bm + tr + i * 16;
        if (r >= M) continue;
        #pragma unroll
        for (int j = 0; j < 4; ++j) {
            int c = bn + tc + j * 16;
            if (c >= N) continue;
            float v = acc[i][j];
            if (bias) v += bias[c];
            if (relu) v = fmaxf(v, 0.f);
            C[(size_t)r * ldc + c] = v;
        }
    }
}

// ---------------- graph helper kernels ----------------
__global__ void count_deg(const int* __restrict__ dst, int* __restrict__ cnt, int E) {
    int t = blockIdx.x * blockDim.x + threadIdx.x;
    if (t < E) atomicAdd(&cnt[dst[t]], 1);
}

__global__ void make_dinv(const int* __restrict__ cnt, float* __restrict__ dinv, int n) {
    int t = blockIdx.x * blockDim.x + threadIdx.x;
    if (t < n) dinv[t] = rsqrtf((float)cnt[t] + 1.0f);
}

// single-block exclusive scan of 65536 counts -> row_ptr[65537]
__global__ __launch_bounds__(1024) void scan_rowptr(const int* __restrict__ cnt,
                                                    int* __restrict__ row_ptr) {
    __shared__ int sums[1024];
    int t = threadIdx.x;
    int base = t * 64;
    int s = 0;
    #pragma unroll 4
    for (int i = 0; i < 64; ++i) s += cnt[base + i];
    sums[t] = s;
    __syncthreads();
    // Hillis-Steele inclusive scan
    for (int off = 1; off < 1024; off <<= 1) {
        int v = sums[t];
        int add = (t >= off) ? sums[t - off] : 0;
        __syncthreads();
        sums[t] = v + add;
        __syncthreads();
    }
    int run = (t == 0) ? 0 : sums[t - 1];
    for (int i = 0; i < 64; ++i) {
        row_ptr[base + i] = run;
        run += cnt[base + i];
    }
    if (t == 1023) row_ptr[N_NODES] = run;
}

// scatter edges into CSR (by dst); coef folded in
__global__ void fill_csr(const int* __restrict__ src, const int* __restrict__ dst,
                         const float* __restrict__ dinv, const int* __restrict__ row_ptr,
                         int* __restrict__ cur, int* __restrict__ csr_src,
                         float* __restrict__ csr_val, int E) {
    int e = blockIdx.x * blockDim.x + threadIdx.x;
    if (e >= E) return;
    int d = dst[e], s = src[e];
    int pos = row_ptr[d] + atomicAdd(&cur[d], 1);
    csr_src[pos] = s;
    csr_val[pos] = dinv[s] * dinv[d];
}

// ax[i,:] = x[i,:]*dinv[i]^2 + sum_{e: dst=i} coef[e]*x[src[e],:]
// thread = (node, feature-pair), float2
__global__ void gather_agg(const float* __restrict__ x, const int* __restrict__ row_ptr,
                           const int* __restrict__ csr_src, const float* __restrict__ csr_val,
                           const float* __restrict__ dinv, float* __restrict__ ax, int F2) {
    int t = blockIdx.x * blockDim.x + threadIdx.x;
    int total = N_NODES * F2;
    if (t >= total) return;
    int i = t / F2;
    int f2 = t - i * F2;
    const float2* xp = (const float2*)x;
    float d = dinv[i];
    float2 xi = xp[(size_t)i * F2 + f2];
    float accx = xi.x * d * d;
    float accy = xi.y * d * d;
    int p0 = row_ptr[i], p1 = row_ptr[i + 1];
    for (int p = p0; p < p1; ++p) {
        int s = csr_src[p];
        float c = csr_val[p];
        float2 xs = xp[(size_t)s * F2 + f2];
        accx = fmaf(c, xs.x, accx);
        accy = fmaf(c, xs.y, accy);
    }
    float2 o; o.x = accx; o.y = accy;
    ((float2*)ax)[(size_t)i * F2 + f2] = o;
}

// global max pool: 64 contiguous nodes per graph
__global__ void pool_max(const float* __restrict__ y, float* __restrict__ out, int F) {
    int g = blockIdx.x;
    for (int f = threadIdx.x; f < F; f += blockDim.x) {
        float m = -INFINITY;
        const float* p = y + (size_t)g * NPG * F + f;
        #pragma unroll 4
        for (int n = 0; n < NPG; ++n) m = fmaxf(m, p[(size_t)n * F]);
        out[(size_t)g * F + f] = m;
    }
}

// ---------------- host side ----------------
static inline void gemm_launch(const float* A, const float* B, const float* bias, float* C,
                               int M, int N, int K, int ldc, int relu, hipStream_t s) {
    dim3 grid((N + TN - 1) / TN, (M + TM - 1) / TM);
    gemm_bias_act<<<grid, 256, 0, s>>>(A, B, bias, C, M, N, K, ldc, relu);
}

extern "C" void kernel_launch(void* const* d_in, const int* in_sizes, int n_in,
                              void* d_out, int out_size, void* d_ws, size_t ws_size,
                              hipStream_t stream) {
    (void)in_sizes; (void)n_in; (void)out_size; (void)ws_size;

    const float* x1     = (const float*)d_in[0];
    const int*   ei1    = (const int*)d_in[1];
    const float* x2     = (const float*)d_in[3];
    const int*   ei2    = (const int*)d_in[4];
    const float* target = (const float*)d_in[6];

    const float* xt_w  = (const float*)d_in[27];
    const float* xt_b  = (const float*)d_in[28];
    const float* fc1_w = (const float*)d_in[29];
    const float* fc1_b = (const float*)d_in[30];
    const float* fc2_w = (const float*)d_in[31];
    const float* fc2_b = (const float*)d_in[32];
    const float* out_w = (const float*)d_in[33];
    const float* out_b = (const float*)d_in[34];

    char* ws = (char*)d_ws;
    // layout (bytes)
    float* A    = (float*)(ws + 0);           // 65536*156*4 = 40,894,464 (agg out / pooled)
    float* Bv   = (float*)(ws + 40894464);    // 40,894,464 (y1/y2 / fc_out)
    float* C    = (float*)(ws + 81788928);    // 65536*312*4 = 81,788,928 (y3)
    int*   cnt  = (int*)  (ws + 163577856);   // 262,144
    float* dinv = (float*)(ws + 163840000);   // 262,144
    int*   rowp = (int*)  (ws + 164102144);   // 262,148 (+pad)
    int*   cur  = (int*)  (ws + 164364800);   // 262,144
    int*   csrs = (int*)  (ws + 164626944);   // 2,097,152
    float* csrv = (float*)(ws + 166724096);   // 2,097,152
    float* xc   = (float*)(ws + 168821248);   // 1024*256*4 = 1,048,576
    float* xc1  = (float*)(ws + 169869824);   // 1024*128*4 = 524,288
    float* xc2  = (float*)(ws + 170394112);   // 1024*32*4  = 131,072

    const int E = N_EDGES;
    const int EB = (E + 255) / 256;
    const int NB = (N_NODES + 255) / 256;

    for (int br = 0; br < 2; ++br) {
        const float* x   = br == 0 ? x1 : x2;
        const int*   ei  = br == 0 ? ei1 : ei2;
        const int*   src = ei;
        const int*   dst = ei + E;
        int base = 7 + br * 10;
        const float* w1    = (const float*)d_in[base + 0];
        const float* b1    = (const float*)d_in[base + 1];
        const float* w2    = (const float*)d_in[base + 2];
        const float* b2    = (const float*)d_in[base + 3];
        const float* w3    = (const float*)d_in[base + 4];
        const float* b3    = (const float*)d_in[base + 5];
        const float* bfc1w = (const float*)d_in[base + 6];
        const float* bfc1b = (const float*)d_in[base + 7];
        const float* bfc2w = (const float*)d_in[base + 8];
        const float* bfc2b = (const float*)d_in[base + 9];

        // ---- CSR build (per branch) ----
        hipMemsetAsync(cnt, 0, N_NODES * sizeof(int), stream);
        hipMemsetAsync(cur, 0, N_NODES * sizeof(int), stream);
        count_deg<<<EB, 256, 0, stream>>>(dst, cnt, E);
        make_dinv<<<NB, 256, 0, stream>>>(cnt, dinv, N_NODES);
        scan_rowptr<<<1, 1024, 0, stream>>>(cnt, rowp);
        fill_csr<<<EB, 256, 0, stream>>>(src, dst, dinv, rowp, cur, csrs, csrv, E);

        // ---- conv1: agg(x)->A, gemm 78->78 ----
        {
            int F = FD, F2 = F / 2;
            int total = N_NODES * F2;
            gather_agg<<<(total + 255) / 256, 256, 0, stream>>>(x, rowp, csrs, csrv, dinv, A, F2);
            gemm_launch(A, w1, b1, Bv, N_NODES, F, F, F, 1, stream);
        }
        // ---- conv2: agg(y1)->A, gemm 78->156 ----
        {
            int F = FD, F2 = F / 2;
            int total = N_NODES * F2;
            gather_agg<<<(total + 255) / 256, 256, 0, stream>>>(Bv, rowp, csrs, csrv, dinv, A, F2);
            gemm_launch(A, w2, b2, Bv, N_NODES, FD * 2, F, FD * 2, 1, stream);
        }
        // ---- conv3: agg(y2)->A, gemm 156->312 ----
        {
            int F = FD * 2, F2 = F / 2;
            int total = N_NODES * F2;
            gather_agg<<<(total + 255) / 256, 256, 0, stream>>>(Bv, rowp, csrs, csrv, dinv, A, F2);
            gemm_launch(A, w3, b3, C, N_NODES, FD * 4, F, FD * 4, 1, stream);
        }

        // ---- pool + branch MLP ----
        float* pooled = A;                 // A free now
        float* fc_out = Bv;                // Bv free now
        pool_max<<<N_GRAPHS, 256, 0, stream>>>(C, pooled, FD * 4);
        gemm_launch(pooled, bfc1w, bfc1b, fc_out, N_GRAPHS, 1024, FD * 4, 1024, 1, stream);
        gemm_launch(fc_out, bfc2w, bfc2b, xc + br * 64, N_GRAPHS, 64, 1024, 256, 0, stream);
    }

    // xt: [1024,1000] @ [1000,128] + b -> xc columns [128..256)
    gemm_launch(target, xt_w, xt_b, xc + 128, N_GRAPHS, 128, 1000, 256, 0, stream);
    // head
    gemm_launch(xc,  fc1_w, fc1_b, xc1, N_GRAPHS, 128, 256, 128, 1, stream);
    gemm_launch(xc1, fc2_w, fc2_b, xc2, N_GRAPHS, 32, 128, 32, 1, stream);
    gemm_launch(xc2, out_w, out_b, (float*)d_out, N_GRAPHS, 1, 32, 1, 0, stream);
}

// Round 3
// 1793.990 us; speedup vs baseline: 3.1863x; 1.0198x over previous
//
#include <hip/hip_runtime.h>
#include <hip/hip_bf16.h>
#include <math.h>

#define N_NODES 65536
#define N_EDGES 524288
#define N_GRAPHS 1024
#define NPG 64
#define FD 78

// ---------------- GEMM: C = A[M,K] @ B[K,N] (+bias) (+relu), row-major, ldc ----------------
// 64x64 tile, 256 threads, 4x4 per thread, f32. For large-M GEMMs only.
#define TM 64
#define TN 64
#define TK 16

__global__ __launch_bounds__(256) void gemm_bias_act(
    const float* __restrict__ A, const float* __restrict__ B,
    const float* __restrict__ bias, float* __restrict__ C,
    int M, int N, int K, int ldc, int relu)
{
    __shared__ float As[TK][TM + 1];
    __shared__ float Bs[TK][TN + 1];
    int tid = threadIdx.x;
    int bm = blockIdx.y * TM;
    int bn = blockIdx.x * TN;
    int tr = tid >> 4;          // 0..15
    int tc = tid & 15;          // 0..15
    float acc[4][4] = {};

    for (int k0 = 0; k0 < K; k0 += TK) {
        #pragma unroll
        for (int i = tid; i < TM * TK; i += 256) {
            int r = i >> 4, c = i & 15;
            float v = 0.f;
            if (k0 + c < K) v = A[(size_t)(bm + r) * K + (k0 + c)];
            As[c][r] = v;
        }
        #pragma unroll
        for (int i = tid; i < TK * TN; i += 256) {
            int r = i >> 6, c = i & 63;
            float v = 0.f;
            if ((k0 + r) < K && (bn + c) < N) v = B[(size_t)(k0 + r) * N + (bn + c)];
            Bs[r][c] = v;
        }
        __syncthreads();
        #pragma unroll
        for (int kk = 0; kk < TK; ++kk) {
            float a[4], b[4];
            #pragma unroll
            for (int i = 0; i < 4; ++i) a[i] = As[kk][tr + i * 16];
            #pragma unroll
            for (int j = 0; j < 4; ++j) b[j] = Bs[kk][tc + j * 16];
            #pragma unroll
            for (int i = 0; i < 4; ++i)
                #pragma unroll
                for (int j = 0; j < 4; ++j)
                    acc[i][j] = fmaf(a[i], b[j], acc[i][j]);
        }
        __syncthreads();
    }
    #pragma unroll
    for (int i = 0; i < 4; ++i) {
        int r = bm + tr + i * 16;
        if (r >= M) continue;
        #pragma unroll
        for (int j = 0; j < 4; ++j) {
            int c = bn + tc + j * 16;
            if (c >= N) continue;
            float v = acc[i][j];
            if (bias) v += bias[c];
            if (relu) v = fmaxf(v, 0.f);
            C[(size_t)r * ldc + c] = v;
        }
    }
}

// ---------------- small/skinny FC: one wave = one row x 4 cols, lanes split K ----------------
// grid: ngroups * ceil(M/4) blocks of 256 (4 waves). Waves in a block share the
// same 4 B-columns (L1 reuse) and cover 4 consecutive rows.
__global__ __launch_bounds__(256) void fc_wave(
    const float* __restrict__ A, const float* __restrict__ B,
    const float* __restrict__ bias, float* __restrict__ C,
    int M, int N, int K, int lda, int ldc, int relu)
{
    int ngroups = (N + 3) >> 2;
    int bid = blockIdx.x;
    int g = bid % ngroups;
    int m = ((bid / ngroups) << 2) + (threadIdx.x >> 6);
    int lane = threadIdx.x & 63;
    if (m >= M) return;
    int n0 = g << 2;
    int rem = N - n0; if (rem > 4) rem = 4;
    const float* a = A + (size_t)m * lda;
    float acc[4] = {0.f, 0.f, 0.f, 0.f};
    for (int k = lane; k < K; k += 64) {
        float av = a[k];
        const float* bp = B + (size_t)k * N + n0;
        #pragma unroll
        for (int j = 0; j < 4; ++j)
            if (j < rem) acc[j] = fmaf(av, bp[j], acc[j]);
    }
    #pragma unroll
    for (int j = 0; j < 4; ++j) {
        float v = acc[j];
        #pragma unroll
        for (int off = 32; off; off >>= 1)
            v += __shfl_xor(v, off, 64);
        acc[j] = v;
    }
    if (lane == 0) {
        #pragma unroll
        for (int j = 0; j < 4; ++j) {
            if (j < rem) {
                float v = acc[j] + (bias ? bias[n0 + j] : 0.f);
                if (relu) v = fmaxf(v, 0.f);
                C[(size_t)m * ldc + n0 + j] = v;
            }
        }
    }
}

// ---------------- graph helper kernels ----------------
__global__ void count_deg(const int* __restrict__ dst, int* __restrict__ cnt, int E) {
    int t = blockIdx.x * blockDim.x + threadIdx.x;
    if (t < E) atomicAdd(&cnt[dst[t]], 1);
}

__global__ void make_dinv(const int* __restrict__ cnt, float* __restrict__ dinv, int n) {
    int t = blockIdx.x * blockDim.x + threadIdx.x;
    if (t < n) dinv[t] = rsqrtf((float)cnt[t] + 1.0f);
}

// single-block exclusive scan of 65536 counts -> row_ptr[65537]
__global__ __launch_bounds__(1024) void scan_rowptr(const int* __restrict__ cnt,
                                                    int* __restrict__ row_ptr) {
    __shared__ int sums[1024];
    int t = threadIdx.x;
    int base = t * 64;
    int s = 0;
    #pragma unroll 4
    for (int i = 0; i < 64; ++i) s += cnt[base + i];
    sums[t] = s;
    __syncthreads();
    for (int off = 1; off < 1024; off <<= 1) {
        int v = sums[t];
        int add = (t >= off) ? sums[t - off] : 0;
        __syncthreads();
        sums[t] = v + add;
        __syncthreads();
    }
    int run = (t == 0) ? 0 : sums[t - 1];
    for (int i = 0; i < 64; ++i) {
        row_ptr[base + i] = run;
        run += cnt[base + i];
    }
    if (t == 1023) row_ptr[N_NODES] = run;
}

// scatter edges into CSR (by dst); coef folded in
__global__ void fill_csr(const int* __restrict__ src, const int* __restrict__ dst,
                         const float* __restrict__ dinv, const int* __restrict__ row_ptr,
                         int* __restrict__ cur, int* __restrict__ csr_src,
                         float* __restrict__ csr_val, int E) {
    int e = blockIdx.x * blockDim.x + threadIdx.x;
    if (e >= E) return;
    int d = dst[e], s = src[e];
    int pos = row_ptr[d] + atomicAdd(&cur[d], 1);
    csr_src[pos] = s;
    csr_val[pos] = dinv[s] * dinv[d];
}

// ax[i,:] = x[i,:]*dinv[i]^2 + sum_{e: dst=i} coef[e]*x[src[e],:]
// thread = (node, feature-pair), float2
__global__ void gather_agg(const float* __restrict__ x, const int* __restrict__ row_ptr,
                           const int* __restrict__ csr_src, const float* __restrict__ csr_val,
                           const float* __restrict__ dinv, float* __restrict__ ax, int F2) {
    int t = blockIdx.x * blockDim.x + threadIdx.x;
    int total = N_NODES * F2;
    if (t >= total) return;
    int i = t / F2;
    int f2 = t - i * F2;
    const float2* xp = (const float2*)x;
    float d = dinv[i];
    float2 xi = xp[(size_t)i * F2 + f2];
    float accx = xi.x * d * d;
    float accy = xi.y * d * d;
    int p0 = row_ptr[i], p1 = row_ptr[i + 1];
    for (int p = p0; p < p1; ++p) {
        int s = csr_src[p];
        float c = csr_val[p];
        float2 xs = xp[(size_t)s * F2 + f2];
        accx = fmaf(c, xs.x, accx);
        accy = fmaf(c, xs.y, accy);
    }
    float2 o; o.x = accx; o.y = accy;
    ((float2*)ax)[(size_t)i * F2 + f2] = o;
}

// global max pool: 64 contiguous nodes per graph
__global__ void pool_max(const float* __restrict__ y, float* __restrict__ out, int F) {
    int g = blockIdx.x;
    for (int f = threadIdx.x; f < F; f += blockDim.x) {
        float m = -INFINITY;
        const float* p = y + (size_t)g * NPG * F + f;
        #pragma unroll 4
        for (int n = 0; n < NPG; ++n) m = fmaxf(m, p[(size_t)n * F]);
        out[(size_t)g * F + f] = m;
    }
}

// ---------------- host side ----------------
static inline void gemm_launch(const float* A, const float* B, const float* bias, float* C,
                               int M, int N, int K, int ldc, int relu, hipStream_t s) {
    dim3 grid((N + TN - 1) / TN, (M + TM - 1) / TM);
    gemm_bias_act<<<grid, 256, 0, s>>>(A, B, bias, C, M, N, K, ldc, relu);
}

static inline void fc_launch(const float* A, const float* B, const float* bias, float* C,
                             int M, int N, int K, int lda, int ldc, int relu, hipStream_t s) {
    int ngroups = (N + 3) / 4;
    int mblocks = (M + 3) / 4;
    fc_wave<<<ngroups * mblocks, 256, 0, s>>>(A, B, bias, C, M, N, K, lda, ldc, relu);
}

extern "C" void kernel_launch(void* const* d_in, const int* in_sizes, int n_in,
                              void* d_out, int out_size, void* d_ws, size_t ws_size,
                              hipStream_t stream) {
    (void)in_sizes; (void)n_in; (void)out_size; (void)ws_size;

    const float* x1     = (const float*)d_in[0];
    const int*   ei1    = (const int*)d_in[1];
    const float* x2     = (const float*)d_in[3];
    const int*   ei2    = (const int*)d_in[4];
    const float* target = (const float*)d_in[6];

    const float* xt_w  = (const float*)d_in[27];
    const float* xt_b  = (const float*)d_in[28];
    const float* fc1_w = (const float*)d_in[29];
    const float* fc1_b = (const float*)d_in[30];
    const float* fc2_w = (const float*)d_in[31];
    const float* fc2_b = (const float*)d_in[32];
    const float* out_w = (const float*)d_in[33];
    const float* out_b = (const float*)d_in[34];

    char* ws = (char*)d_ws;
    float* A    = (float*)(ws + 0);           // 65536*156*4 = 40,894,464 (agg out / pooled)
    float* Bv   = (float*)(ws + 40894464);    // 40,894,464 (y1/y2 / fc_out)
    float* C    = (float*)(ws + 81788928);    // 65536*312*4 = 81,788,928 (y3)
    int*   cnt  = (int*)  (ws + 163577856);   // 262,144
    float* dinv = (float*)(ws + 163840000);   // 262,144
    int*   rowp = (int*)  (ws + 164102144);   // 262,148 (+pad)
    int*   cur  = (int*)  (ws + 164364800);   // 262,144
    int*   csrs = (int*)  (ws + 164626944);   // 2,097,152
    float* csrv = (float*)(ws + 166724096);   // 2,097,152
    float* xc   = (float*)(ws + 168821248);   // 1024*256*4 = 1,048,576
    float* xc1  = (float*)(ws + 169869824);   // 1024*128*4 = 524,288
    float* xc2  = (float*)(ws + 170394112);   // 1024*32*4  = 131,072

    const int E = N_EDGES;
    const int EB = (E + 255) / 256;
    const int NB = (N_NODES + 255) / 256;

    for (int br = 0; br < 2; ++br) {
        const float* x   = br == 0 ? x1 : x2;
        const int*   ei  = br == 0 ? ei1 : ei2;
        const int*   src = ei;
        const int*   dst = ei + E;
        int base = 7 + br * 10;
        const float* w1    = (const float*)d_in[base + 0];
        const float* b1    = (const float*)d_in[base + 1];
        const float* w2    = (const float*)d_in[base + 2];
        const float* b2    = (const float*)d_in[base + 3];
        const float* w3    = (const float*)d_in[base + 4];
        const float* b3    = (const float*)d_in[base + 5];
        const float* bfc1w = (const float*)d_in[base + 6];
        const float* bfc1b = (const float*)d_in[base + 7];
        const float* bfc2w = (const float*)d_in[base + 8];
        const float* bfc2b = (const float*)d_in[base + 9];

        // ---- CSR build (per branch) ----
        hipMemsetAsync(cnt, 0, N_NODES * sizeof(int), stream);
        hipMemsetAsync(cur, 0, N_NODES * sizeof(int), stream);
        count_deg<<<EB, 256, 0, stream>>>(dst, cnt, E);
        make_dinv<<<NB, 256, 0, stream>>>(cnt, dinv, N_NODES);
        scan_rowptr<<<1, 1024, 0, stream>>>(cnt, rowp);
        fill_csr<<<EB, 256, 0, stream>>>(src, dst, dinv, rowp, cur, csrs, csrv, E);

        // ---- conv1: agg(x)->A, gemm 78->78 ----
        {
            int F = FD, F2 = F / 2;
            int total = N_NODES * F2;
            gather_agg<<<(total + 255) / 256, 256, 0, stream>>>(x, rowp, csrs, csrv, dinv, A, F2);
            gemm_launch(A, w1, b1, Bv, N_NODES, F, F, F, 1, stream);
        }
        // ---- conv2: agg(y1)->A, gemm 78->156 ----
        {
            int F = FD, F2 = F / 2;
            int total = N_NODES * F2;
            gather_agg<<<(total + 255) / 256, 256, 0, stream>>>(Bv, rowp, csrs, csrv, dinv, A, F2);
            gemm_launch(A, w2, b2, Bv, N_NODES, FD * 2, F, FD * 2, 1, stream);
        }
        // ---- conv3: agg(y2)->A, gemm 156->312 ----
        {
            int F = FD * 2, F2 = F / 2;
            int total = N_NODES * F2;
            gather_agg<<<(total + 255) / 256, 256, 0, stream>>>(Bv, rowp, csrs, csrv, dinv, A, F2);
            gemm_launch(A, w3, b3, C, N_NODES, FD * 4, F, FD * 4, 1, stream);
        }

        // ---- pool + branch MLP ----
        float* pooled = A;                 // A free now
        float* fc_out = Bv;                // Bv free now
        pool_max<<<N_GRAPHS, 256, 0, stream>>>(C, pooled, FD * 4);
        // fc1: [1024,312]@[312,1024] (wide N, tiled w/ grid 256)
        gemm_launch(pooled, bfc1w, bfc1b, fc_out, N_GRAPHS, 1024, FD * 4, 1024, 1, stream);
        // fc2: [1024,1024]@[1024,64] -> wave kernel
        fc_launch(fc_out, bfc2w, bfc2b, xc + br * 64, N_GRAPHS, 64, 1024, 1024, 256, 0, stream);
    }

    // xt: [1024,1000] @ [1000,128] + b -> xc columns [128..256)
    fc_launch(target, xt_w, xt_b, xc + 128, N_GRAPHS, 128, 1000, 1000, 256, 0, stream);
    // head
    fc_launch(xc,  fc1_w, fc1_b, xc1, N_GRAPHS, 128, 256, 256, 128, 1, stream);
    fc_launch(xc1, fc2_w, fc2_b, xc2, N_GRAPHS, 32, 128, 128, 32, 1, stream);
    fc_launch(xc2, out_w, out_b, (float*)d_out, N_GRAPHS, 1, 32, 32, 1, 0, stream);
}

// Round 4
// 1378.988 us; speedup vs baseline: 4.1452x; 1.3009x over previous
//
#include <hip/hip_runtime.h>
#include <hip/hip_bf16.h>
#include <math.h>

#define N_NODES 65536
#define N_EDGES 524288
#define N_GRAPHS 1024
#define NPG 64
#define FD 78

// ---------------- GEMM: C = A[M,K] @ B[K,N] (+bias) (+relu), row-major, ldc ----------------
// 64x64 tile, 256 threads, 4x4 per thread, f32. For large-M GEMMs only.
#define TM 64
#define TN 64
#define TK 16

__global__ __launch_bounds__(256) void gemm_bias_act(
    const float* __restrict__ A, const float* __restrict__ B,
    const float* __restrict__ bias, float* __restrict__ C,
    int M, int N, int K, int ldc, int relu)
{
    __shared__ float As[TK][TM + 1];
    __shared__ float Bs[TK][TN + 1];
    int tid = threadIdx.x;
    int bm = blockIdx.y * TM;
    int bn = blockIdx.x * TN;
    int tr = tid >> 4;          // 0..15
    int tc = tid & 15;          // 0..15
    float acc[4][4] = {};

    for (int k0 = 0; k0 < K; k0 += TK) {
        #pragma unroll
        for (int i = tid; i < TM * TK; i += 256) {
            int r = i >> 4, c = i & 15;
            float v = 0.f;
            if (k0 + c < K) v = A[(size_t)(bm + r) * K + (k0 + c)];
            As[c][r] = v;
        }
        #pragma unroll
        for (int i = tid; i < TK * TN; i += 256) {
            int r = i >> 6, c = i & 63;
            float v = 0.f;
            if ((k0 + r) < K && (bn + c) < N) v = B[(size_t)(k0 + r) * N + (bn + c)];
            Bs[r][c] = v;
        }
        __syncthreads();
        #pragma unroll
        for (int kk = 0; kk < TK; ++kk) {
            float a[4], b[4];
            #pragma unroll
            for (int i = 0; i < 4; ++i) a[i] = As[kk][tr + i * 16];
            #pragma unroll
            for (int j = 0; j < 4; ++j) b[j] = Bs[kk][tc + j * 16];
            #pragma unroll
            for (int i = 0; i < 4; ++i)
                #pragma unroll
                for (int j = 0; j < 4; ++j)
                    acc[i][j] = fmaf(a[i], b[j], acc[i][j]);
        }
        __syncthreads();
    }
    #pragma unroll
    for (int i = 0; i < 4; ++i) {
        int r = bm + tr + i * 16;
        if (r >= M) continue;
        #pragma unroll
        for (int j = 0; j < 4; ++j) {
            int c = bn + tc + j * 16;
            if (c >= N) continue;
            float v = acc[i][j];
            if (bias) v += bias[c];
            if (relu) v = fmaxf(v, 0.f);
            C[(size_t)r * ldc + c] = v;
        }
    }
}

// ---------------- small-M FC: one wave = one row x 64 consecutive cols ----------------
// lanes map to N (coalesced B row reads); a[k] is a wave-uniform broadcast.
// Block = 4 waves = 4 consecutive rows sharing the same B columns (L1/L2 reuse).
__global__ __launch_bounds__(256) void fc_row(
    const float* __restrict__ A, const float* __restrict__ B,
    const float* __restrict__ bias, float* __restrict__ C,
    int M, int N, int K, int lda, int ldc, int relu)
{
    int nchunks = (N + 63) >> 6;
    int bid = blockIdx.x;
    int nc = bid % nchunks;
    int m = ((bid / nchunks) << 2) + (threadIdx.x >> 6);
    int lane = threadIdx.x & 63;
    if (m >= M) return;
    int n = (nc << 6) + lane;
    int nclamp = n < N ? n : N - 1;          // keep loads in-bounds, all lanes uniform-flow
    const float* __restrict__ a = A + (size_t)m * lda;
    const float* __restrict__ bp = B + nclamp;
    float acc = 0.f;
    int kk = 0;
    #pragma unroll 4
    for (; kk + 4 <= K; kk += 4) {
        float a0 = a[kk + 0], a1 = a[kk + 1], a2 = a[kk + 2], a3 = a[kk + 3];
        float b0 = bp[(size_t)(kk + 0) * N];
        float b1 = bp[(size_t)(kk + 1) * N];
        float b2 = bp[(size_t)(kk + 2) * N];
        float b3 = bp[(size_t)(kk + 3) * N];
        acc = fmaf(a0, b0, acc);
        acc = fmaf(a1, b1, acc);
        acc = fmaf(a2, b2, acc);
        acc = fmaf(a3, b3, acc);
    }
    for (; kk < K; ++kk)
        acc = fmaf(a[kk], bp[(size_t)kk * N], acc);
    if (n < N) {
        float v = acc + bias[n];
        if (relu) v = fmaxf(v, 0.f);
        C[(size_t)m * ldc + n] = v;
    }
}

// ---------------- graph helper kernels ----------------
__global__ void count_deg(const int* __restrict__ dst, int* __restrict__ cnt, int E) {
    int t = blockIdx.x * blockDim.x + threadIdx.x;
    if (t < E) atomicAdd(&cnt[dst[t]], 1);
}

__global__ void make_dinv(const int* __restrict__ cnt, float* __restrict__ dinv, int n) {
    int t = blockIdx.x * blockDim.x + threadIdx.x;
    if (t < n) dinv[t] = rsqrtf((float)cnt[t] + 1.0f);
}

// single-block exclusive scan of 65536 counts -> row_ptr[65537]
__global__ __launch_bounds__(1024) void scan_rowptr(const int* __restrict__ cnt,
                                                    int* __restrict__ row_ptr) {
    __shared__ int sums[1024];
    int t = threadIdx.x;
    int base = t * 64;
    int s = 0;
    #pragma unroll 4
    for (int i = 0; i < 64; ++i) s += cnt[base + i];
    sums[t] = s;
    __syncthreads();
    for (int off = 1; off < 1024; off <<= 1) {
        int v = sums[t];
        int add = (t >= off) ? sums[t - off] : 0;
        __syncthreads();
        sums[t] = v + add;
        __syncthreads();
    }
    int run = (t == 0) ? 0 : sums[t - 1];
    for (int i = 0; i < 64; ++i) {
        row_ptr[base + i] = run;
        run += cnt[base + i];
    }
    if (t == 1023) row_ptr[N_NODES] = run;
}

// scatter edges into CSR (by dst); coef folded in
__global__ void fill_csr(const int* __restrict__ src, const int* __restrict__ dst,
                         const float* __restrict__ dinv, const int* __restrict__ row_ptr,
                         int* __restrict__ cur, int* __restrict__ csr_src,
                         float* __restrict__ csr_val, int E) {
    int e = blockIdx.x * blockDim.x + threadIdx.x;
    if (e >= E) return;
    int d = dst[e], s = src[e];
    int pos = row_ptr[d] + atomicAdd(&cur[d], 1);
    csr_src[pos] = s;
    csr_val[pos] = dinv[s] * dinv[d];
}

// ax[i,:] = x[i,:]*dinv[i]^2 + sum_{e: dst=i} coef[e]*x[src[e],:]
// thread = (node, feature-pair), float2
__global__ void gather_agg(const float* __restrict__ x, const int* __restrict__ row_ptr,
                           const int* __restrict__ csr_src, const float* __restrict__ csr_val,
                           const float* __restrict__ dinv, float* __restrict__ ax, int F2) {
    int t = blockIdx.x * blockDim.x + threadIdx.x;
    int total = N_NODES * F2;
    if (t >= total) return;
    int i = t / F2;
    int f2 = t - i * F2;
    const float2* xp = (const float2*)x;
    float d = dinv[i];
    float2 xi = xp[(size_t)i * F2 + f2];
    float accx = xi.x * d * d;
    float accy = xi.y * d * d;
    int p0 = row_ptr[i], p1 = row_ptr[i + 1];
    for (int p = p0; p < p1; ++p) {
        int s = csr_src[p];
        float c = csr_val[p];
        float2 xs = xp[(size_t)s * F2 + f2];
        accx = fmaf(c, xs.x, accx);
        accy = fmaf(c, xs.y, accy);
    }
    float2 o; o.x = accx; o.y = accy;
    ((float2*)ax)[(size_t)i * F2 + f2] = o;
}

// global max pool: 64 contiguous nodes per graph
__global__ void pool_max(const float* __restrict__ y, float* __restrict__ out, int F) {
    int g = blockIdx.x;
    for (int f = threadIdx.x; f < F; f += blockDim.x) {
        float m = -INFINITY;
        const float* p = y + (size_t)g * NPG * F + f;
        #pragma unroll 4
        for (int n = 0; n < NPG; ++n) m = fmaxf(m, p[(size_t)n * F]);
        out[(size_t)g * F + f] = m;
    }
}

// ---------------- host side ----------------
static inline void gemm_launch(const float* A, const float* B, const float* bias, float* C,
                               int M, int N, int K, int ldc, int relu, hipStream_t s) {
    dim3 grid((N + TN - 1) / TN, (M + TM - 1) / TM);
    gemm_bias_act<<<grid, 256, 0, s>>>(A, B, bias, C, M, N, K, ldc, relu);
}

static inline void fc_launch(const float* A, const float* B, const float* bias, float* C,
                             int M, int N, int K, int lda, int ldc, int relu, hipStream_t s) {
    int nchunks = (N + 63) / 64;
    int mblocks = (M + 3) / 4;
    fc_row<<<nchunks * mblocks, 256, 0, s>>>(A, B, bias, C, M, N, K, lda, ldc, relu);
}

extern "C" void kernel_launch(void* const* d_in, const int* in_sizes, int n_in,
                              void* d_out, int out_size, void* d_ws, size_t ws_size,
                              hipStream_t stream) {
    (void)in_sizes; (void)n_in; (void)out_size; (void)ws_size;

    const float* x1     = (const float*)d_in[0];
    const int*   ei1    = (const int*)d_in[1];
    const float* x2     = (const float*)d_in[3];
    const int*   ei2    = (const int*)d_in[4];
    const float* target = (const float*)d_in[6];

    const float* xt_w  = (const float*)d_in[27];
    const float* xt_b  = (const float*)d_in[28];
    const float* fc1_w = (const float*)d_in[29];
    const float* fc1_b = (const float*)d_in[30];
    const float* fc2_w = (const float*)d_in[31];
    const float* fc2_b = (const float*)d_in[32];
    const float* out_w = (const float*)d_in[33];
    const float* out_b = (const float*)d_in[34];

    char* ws = (char*)d_ws;
    float* A    = (float*)(ws + 0);           // 65536*156*4 = 40,894,464 (agg out / pooled)
    float* Bv   = (float*)(ws + 40894464);    // 40,894,464 (y1/y2 / fc_out)
    float* C    = (float*)(ws + 81788928);    // 65536*312*4 = 81,788,928 (y3)
    int*   cnt  = (int*)  (ws + 163577856);   // 262,144
    float* dinv = (float*)(ws + 163840000);   // 262,144
    int*   rowp = (int*)  (ws + 164102144);   // 262,148 (+pad)
    int*   cur  = (int*)  (ws + 164364800);   // 262,144
    int*   csrs = (int*)  (ws + 164626944);   // 2,097,152
    float* csrv = (float*)(ws + 166724096);   // 2,097,152
    float* xc   = (float*)(ws + 168821248);   // 1024*256*4 = 1,048,576
    float* xc1  = (float*)(ws + 169869824);   // 1024*128*4 = 524,288
    float* xc2  = (float*)(ws + 170394112);   // 1024*32*4  = 131,072

    const int E = N_EDGES;
    const int EB = (E + 255) / 256;
    const int NB = (N_NODES + 255) / 256;

    for (int br = 0; br < 2; ++br) {
        const float* x   = br == 0 ? x1 : x2;
        const int*   ei  = br == 0 ? ei1 : ei2;
        const int*   src = ei;
        const int*   dst = ei + E;
        int base = 7 + br * 10;
        const float* w1    = (const float*)d_in[base + 0];
        const float* b1    = (const float*)d_in[base + 1];
        const float* w2    = (const float*)d_in[base + 2];
        const float* b2    = (const float*)d_in[base + 3];
        const float* w3    = (const float*)d_in[base + 4];
        const float* b3    = (const float*)d_in[base + 5];
        const float* bfc1w = (const float*)d_in[base + 6];
        const float* bfc1b = (const float*)d_in[base + 7];
        const float* bfc2w = (const float*)d_in[base + 8];
        const float* bfc2b = (const float*)d_in[base + 9];

        // ---- CSR build (per branch) ----
        hipMemsetAsync(cnt, 0, N_NODES * sizeof(int), stream);
        hipMemsetAsync(cur, 0, N_NODES * sizeof(int), stream);
        count_deg<<<EB, 256, 0, stream>>>(dst, cnt, E);
        make_dinv<<<NB, 256, 0, stream>>>(cnt, dinv, N_NODES);
        scan_rowptr<<<1, 1024, 0, stream>>>(cnt, rowp);
        fill_csr<<<EB, 256, 0, stream>>>(src, dst, dinv, rowp, cur, csrs, csrv, E);

        // ---- conv1: agg(x)->A, gemm 78->78 ----
        {
            int F = FD, F2 = F / 2;
            int total = N_NODES * F2;
            gather_agg<<<(total + 255) / 256, 256, 0, stream>>>(x, rowp, csrs, csrv, dinv, A, F2);
            gemm_launch(A, w1, b1, Bv, N_NODES, F, F, F, 1, stream);
        }
        // ---- conv2: agg(y1)->A, gemm 78->156 ----
        {
            int F = FD, F2 = F / 2;
            int total = N_NODES * F2;
            gather_agg<<<(total + 255) / 256, 256, 0, stream>>>(Bv, rowp, csrs, csrv, dinv, A, F2);
            gemm_launch(A, w2, b2, Bv, N_NODES, FD * 2, F, FD * 2, 1, stream);
        }
        // ---- conv3: agg(y2)->A, gemm 156->312 ----
        {
            int F = FD * 2, F2 = F / 2;
            int total = N_NODES * F2;
            gather_agg<<<(total + 255) / 256, 256, 0, stream>>>(Bv, rowp, csrs, csrv, dinv, A, F2);
            gemm_launch(A, w3, b3, C, N_NODES, FD * 4, F, FD * 4, 1, stream);
        }

        // ---- pool + branch MLP ----
        float* pooled = A;                 // A free now
        float* fc_out = Bv;                // Bv free now
        pool_max<<<N_GRAPHS, 256, 0, stream>>>(C, pooled, FD * 4);
        // fc1: [1024,312]@[312,1024] + b, relu
        fc_launch(pooled, bfc1w, bfc1b, fc_out, N_GRAPHS, 1024, FD * 4, FD * 4, 1024, 1, stream);
        // fc2: [1024,1024]@[1024,64] + b
        fc_launch(fc_out, bfc2w, bfc2b, xc + br * 64, N_GRAPHS, 64, 1024, 1024, 256, 0, stream);
    }

    // xt: [1024,1000] @ [1000,128] + b -> xc columns [128..256)
    fc_launch(target, xt_w, xt_b, xc + 128, N_GRAPHS, 128, 1000, 1000, 256, 0, stream);
    // head
    fc_launch(xc,  fc1_w, fc1_b, xc1, N_GRAPHS, 128, 256, 256, 128, 1, stream);
    fc_launch(xc1, fc2_w, fc2_b, xc2, N_GRAPHS, 32, 128, 128, 32, 1, stream);
    fc_launch(xc2, out_w, out_b, (float*)d_out, N_GRAPHS, 1, 32, 32, 1, 0, stream);
}

// Round 5
// 1098.781 us; speedup vs baseline: 5.2023x; 1.2550x over previous
//
#include <hip/hip_runtime.h>
#include <hip/hip_bf16.h>
#include <math.h>

#define N_NODES 65536
#define N_EDGES 524288
#define N_GRAPHS 1024
#define NPG 64
#define FD 78

typedef __attribute__((ext_vector_type(8))) short bf16x8;
typedef __attribute__((ext_vector_type(4))) float f32x4;

__device__ __forceinline__ unsigned short f2bf(float v) {
    unsigned int u = __float_as_uint(v);
    unsigned int r = (u + 0x7FFFu + ((u >> 16) & 1u)) >> 16;
    return (unsigned short)r;
}
__device__ __forceinline__ float bf2f(unsigned short h) {
    return __uint_as_float(((unsigned int)h) << 16);
}

// ---------------- split-bf16 MFMA GEMM ----------------
// C[M,N] = A[M,Kp] @ Wt[Np,Kp]^T (+bias, +relu). A given as hi/lo bf16, W as
// transposed hi/lo bf16 [Np][Kp], zero-padded. 3-pass split: Ah*Wh + Ah*Wl + Al*Wh.
// Block: 256 thr = 4 waves (2x2), tile 128x128, wave tile 64x64 (4x4 frags 16x16).
__global__ __launch_bounds__(256) void gemm_mfma_split(
    const unsigned short* __restrict__ Ah, const unsigned short* __restrict__ Al,
    const unsigned short* __restrict__ Wh, const unsigned short* __restrict__ Wl,
    const float* __restrict__ bias, float* __restrict__ C,
    int N, int Kp)
{
    __shared__ __align__(16) unsigned short sAh[128][40];
    __shared__ __align__(16) unsigned short sAl[128][40];
    __shared__ __align__(16) unsigned short sBh[128][40];
    __shared__ __align__(16) unsigned short sBl[128][40];

    int tid = threadIdx.x;
    int bm = blockIdx.y << 7;
    int bn = blockIdx.x << 7;
    int lane = tid & 63;
    int wid = tid >> 6;
    int wr = wid >> 1, wc = wid & 1;
    int cr = lane & 15;          // row (A) / col (B) within frag
    int kg = lane >> 4;          // k-group (8 elems)

    f32x4 acc[4][4] = {};

    for (int k0 = 0; k0 < Kp; k0 += 32) {
        // stage A hi/lo: 128 rows x 32 k, 4 segs of 8 bf16 per row
        #pragma unroll
        for (int s = tid; s < 512; s += 256) {
            int r = s >> 2, seg = s & 3;
            *(uint4*)&sAh[r][seg * 8] =
                *(const uint4*)(Ah + (size_t)(bm + r) * Kp + k0 + seg * 8);
        }
        #pragma unroll
        for (int s = tid; s < 512; s += 256) {
            int r = s >> 2, seg = s & 3;
            *(uint4*)&sAl[r][seg * 8] =
                *(const uint4*)(Al + (size_t)(bm + r) * Kp + k0 + seg * 8);
        }
        // stage B hi/lo (Wt rows = output cols)
        #pragma unroll
        for (int s = tid; s < 512; s += 256) {
            int r = s >> 2, seg = s & 3;
            *(uint4*)&sBh[r][seg * 8] =
                *(const uint4*)(Wh + (size_t)(bn + r) * Kp + k0 + seg * 8);
        }
        #pragma unroll
        for (int s = tid; s < 512; s += 256) {
            int r = s >> 2, seg = s & 3;
            *(uint4*)&sBl[r][seg * 8] =
                *(const uint4*)(Wl + (size_t)(bn + r) * Kp + k0 + seg * 8);
        }
        __syncthreads();

        bf16x8 bH[4], bL[4];
        #pragma unroll
        for (int nf = 0; nf < 4; ++nf) {
            bH[nf] = *(const bf16x8*)&sBh[wc * 64 + nf * 16 + cr][kg * 8];
            bL[nf] = *(const bf16x8*)&sBl[wc * 64 + nf * 16 + cr][kg * 8];
        }
        #pragma unroll
        for (int mf = 0; mf < 4; ++mf) {
            bf16x8 aH = *(const bf16x8*)&sAh[wr * 64 + mf * 16 + cr][kg * 8];
            bf16x8 aL = *(const bf16x8*)&sAl[wr * 64 + mf * 16 + cr][kg * 8];
            #pragma unroll
            for (int nf = 0; nf < 4; ++nf) {
                acc[mf][nf] = __builtin_amdgcn_mfma_f32_16x16x32_bf16(aH, bH[nf], acc[mf][nf], 0, 0, 0);
                acc[mf][nf] = __builtin_amdgcn_mfma_f32_16x16x32_bf16(aH, bL[nf], acc[mf][nf], 0, 0, 0);
                acc[mf][nf] = __builtin_amdgcn_mfma_f32_16x16x32_bf16(aL, bH[nf], acc[mf][nf], 0, 0, 0);
            }
        }
        __syncthreads();
    }

    // epilogue: C/D layout col=lane&15, row=(lane>>4)*4+reg
    #pragma unroll
    for (int mf = 0; mf < 4; ++mf) {
        int rowbase = bm + wr * 64 + mf * 16 + kg * 4;
        #pragma unroll
        for (int nf = 0; nf < 4; ++nf) {
            int col = bn + wc * 64 + nf * 16 + cr;
            if (col < N) {
                float bv = bias[col];
                f32x4 v = acc[mf][nf];
                #pragma unroll
                for (int j = 0; j < 4; ++j) {
                    float o = v[j] + bv;
                    o = fmaxf(o, 0.f);
                    C[(size_t)(rowbase + j) * N + col] = o;
                }
            }
        }
    }
}

// ---------------- weight prep: W[K,N] f32 -> Wt hi/lo bf16 [Np][Kp] ----------------
__global__ void prep_w(const float* __restrict__ W, unsigned short* __restrict__ Wh,
                       unsigned short* __restrict__ Wl, int K, int N, int Kp, int Np) {
    int t = blockIdx.x * blockDim.x + threadIdx.x;
    if (t >= Np * Kp) return;
    int n = t / Kp, k = t - n * Kp;
    float v = (n < N && k < K) ? W[(size_t)k * N + n] : 0.f;
    unsigned short h = f2bf(v);
    float lo = v - bf2f(h);
    Wh[t] = h;
    Wl[t] = f2bf(lo);
}

// ---------------- small-M FC: one wave = one row x 64 consecutive cols ----------------
__global__ __launch_bounds__(256) void fc_row(
    const float* __restrict__ A, const float* __restrict__ B,
    const float* __restrict__ bias, float* __restrict__ C,
    int M, int N, int K, int lda, int ldc, int relu)
{
    int nchunks = (N + 63) >> 6;
    int bid = blockIdx.x;
    int nc = bid % nchunks;
    int m = ((bid / nchunks) << 2) + (threadIdx.x >> 6);
    int lane = threadIdx.x & 63;
    if (m >= M) return;
    int n = (nc << 6) + lane;
    int nclamp = n < N ? n : N - 1;
    const float* __restrict__ a = A + (size_t)m * lda;
    const float* __restrict__ bp = B + nclamp;
    float acc = 0.f;
    int kk = 0;
    #pragma unroll 4
    for (; kk + 4 <= K; kk += 4) {
        float a0 = a[kk + 0], a1 = a[kk + 1], a2 = a[kk + 2], a3 = a[kk + 3];
        float b0 = bp[(size_t)(kk + 0) * N];
        float b1 = bp[(size_t)(kk + 1) * N];
        float b2 = bp[(size_t)(kk + 2) * N];
        float b3 = bp[(size_t)(kk + 3) * N];
        acc = fmaf(a0, b0, acc);
        acc = fmaf(a1, b1, acc);
        acc = fmaf(a2, b2, acc);
        acc = fmaf(a3, b3, acc);
    }
    for (; kk < K; ++kk)
        acc = fmaf(a[kk], bp[(size_t)kk * N], acc);
    if (n < N) {
        float v = acc + bias[n];
        if (relu) v = fmaxf(v, 0.f);
        C[(size_t)m * ldc + n] = v;
    }
}

// ---------------- graph helper kernels ----------------
__global__ void count_deg(const int* __restrict__ dst, int* __restrict__ cnt, int E) {
    int t = blockIdx.x * blockDim.x + threadIdx.x;
    if (t < E) atomicAdd(&cnt[dst[t]], 1);
}

__global__ void make_dinv(const int* __restrict__ cnt, float* __restrict__ dinv, int n) {
    int t = blockIdx.x * blockDim.x + threadIdx.x;
    if (t < n) dinv[t] = rsqrtf((float)cnt[t] + 1.0f);
}

__global__ __launch_bounds__(1024) void scan_rowptr(const int* __restrict__ cnt,
                                                    int* __restrict__ row_ptr) {
    __shared__ int sums[1024];
    int t = threadIdx.x;
    int base = t * 64;
    int s = 0;
    #pragma unroll 4
    for (int i = 0; i < 64; ++i) s += cnt[base + i];
    sums[t] = s;
    __syncthreads();
    for (int off = 1; off < 1024; off <<= 1) {
        int v = sums[t];
        int add = (t >= off) ? sums[t - off] : 0;
        __syncthreads();
        sums[t] = v + add;
        __syncthreads();
    }
    int run = (t == 0) ? 0 : sums[t - 1];
    for (int i = 0; i < 64; ++i) {
        row_ptr[base + i] = run;
        run += cnt[base + i];
    }
    if (t == 1023) row_ptr[N_NODES] = run;
}

__global__ void fill_csr(const int* __restrict__ src, const int* __restrict__ dst,
                         const int* __restrict__ row_ptr, int* __restrict__ cur,
                         int* __restrict__ csr_src, int E) {
    int e = blockIdx.x * blockDim.x + threadIdx.x;
    if (e >= E) return;
    int d = dst[e];
    int pos = row_ptr[d] + atomicAdd(&cur[d], 1);
    csr_src[pos] = src[e];
}

// gather + normalize + split to bf16 hi/lo, zero-padded to Kp columns.
// thread = (node, feature-pair)
__global__ void gather_split(const float* __restrict__ x, const int* __restrict__ rowp,
                             const int* __restrict__ csrs, const float* __restrict__ dinv,
                             unsigned short* __restrict__ Ah, unsigned short* __restrict__ Al,
                             int F, int Kp) {
    int Kp2 = Kp >> 1;
    int t = blockIdx.x * blockDim.x + threadIdx.x;
    int total = N_NODES * Kp2;
    if (t >= total) return;
    int i = t / Kp2;
    int f2 = t - i * Kp2;
    size_t obase = (size_t)i * Kp + 2 * f2;
    if (2 * f2 >= F) {
        *(unsigned int*)&Ah[obase] = 0u;
        *(unsigned int*)&Al[obase] = 0u;
        return;
    }
    float di = dinv[i];
    float2 xi = *(const float2*)(x + (size_t)i * F + 2 * f2);
    float ax = xi.x * di * di;
    float ay = xi.y * di * di;
    int p0 = rowp[i], p1 = rowp[i + 1];
    for (int p = p0; p < p1; ++p) {
        int s = csrs[p];
        float c = dinv[s] * di;
        float2 xs = *(const float2*)(x + (size_t)s * F + 2 * f2);
        ax = fmaf(c, xs.x, ax);
        ay = fmaf(c, xs.y, ay);
    }
    unsigned short hx = f2bf(ax), hy = f2bf(ay);
    unsigned short lx = f2bf(ax - bf2f(hx)), ly = f2bf(ay - bf2f(hy));
    *(unsigned int*)&Ah[obase] = (unsigned int)hx | ((unsigned int)hy << 16);
    *(unsigned int*)&Al[obase] = (unsigned int)lx | ((unsigned int)ly << 16);
}

// global max pool: 64 contiguous nodes per graph
__global__ void pool_max(const float* __restrict__ y, float* __restrict__ out, int F) {
    int g = blockIdx.x;
    for (int f = threadIdx.x; f < F; f += blockDim.x) {
        float m = -INFINITY;
        const float* p = y + (size_t)g * NPG * F + f;
        #pragma unroll 4
        for (int n = 0; n < NPG; ++n) m = fmaxf(m, p[(size_t)n * F]);
        out[(size_t)g * F + f] = m;
    }
}

// ---------------- host side ----------------
static inline void fc_launch(const float* A, const float* B, const float* bias, float* C,
                             int M, int N, int K, int lda, int ldc, int relu, hipStream_t s) {
    int nchunks = (N + 63) / 64;
    int mblocks = (M + 3) / 4;
    fc_row<<<nchunks * mblocks, 256, 0, s>>>(A, B, bias, C, M, N, K, lda, ldc, relu);
}

extern "C" void kernel_launch(void* const* d_in, const int* in_sizes, int n_in,
                              void* d_out, int out_size, void* d_ws, size_t ws_size,
                              hipStream_t stream) {
    (void)in_sizes; (void)n_in; (void)out_size; (void)ws_size;

    const float* x1     = (const float*)d_in[0];
    const int*   ei1    = (const int*)d_in[1];
    const float* x2     = (const float*)d_in[3];
    const int*   ei2    = (const int*)d_in[4];
    const float* target = (const float*)d_in[6];

    const float* xt_w  = (const float*)d_in[27];
    const float* xt_b  = (const float*)d_in[28];
    const float* fc1_w = (const float*)d_in[29];
    const float* fc1_b = (const float*)d_in[30];
    const float* fc2_w = (const float*)d_in[31];
    const float* fc2_b = (const float*)d_in[32];
    const float* out_w = (const float*)d_in[33];
    const float* out_b = (const float*)d_in[34];

    char* ws = (char*)d_ws;
    float*          R1   = (float*)(ws + 0);           // 81,788,928  (y1 / y3)
    float*          R2   = (float*)(ws + 81788928);    // 40,894,464  (y2 / pooled / fc_out)
    unsigned short* Ahb  = (unsigned short*)(ws + 122683392); // 20,971,520
    unsigned short* Alb  = (unsigned short*)(ws + 143654912); // 20,971,520
    int*   cnt  = (int*)  (ws + 164626432);            // 262,144 (also 'cur')
    float* dinv = (float*)(ws + 164888576);            // 262,144
    int*   rowp = (int*)  (ws + 165150720);            // 262,148 (+pad)
    int*   csrs = (int*)  (ws + 165413120);            // 2,097,152
    float* xc   = (float*)(ws + 167510272);            // 1,048,576
    float* xc1  = (float*)(ws + 168558848);            // 524,288
    float* xc2  = (float*)(ws + 169083136);            // 131,072
    unsigned short* wt = (unsigned short*)(ws + 169214208); // 786,432 B

    const int E = N_EDGES;
    const int EB = (E + 255) / 256;
    const int NB = (N_NODES + 255) / 256;

    // conv geometry: (K, N, Kp, Np)
    const int Ks[3]  = { FD, FD, FD * 2 };
    const int Ns[3]  = { FD, FD * 2, FD * 4 };
    const int Kps[3] = { 96, 96, 160 };
    const int Nps[3] = { 128, 256, 384 };
    // wt offsets (elems): per branch: c1h,c1l,c2h,c2l,c3h,c3l
    const int wtoff[3] = { 0, 24576, 73728 };   // start of conv c (hi), lo = +Np*Kp
    const int WT_BRANCH = 196608;

    // ---- prep all weights ----
    for (int br = 0; br < 2; ++br) {
        int base = 7 + br * 10;
        for (int c = 0; c < 3; ++c) {
            const float* W = (const float*)d_in[base + 2 * c];
            unsigned short* wh = wt + br * WT_BRANCH + wtoff[c];
            unsigned short* wl = wh + Nps[c] * Kps[c];
            int tot = Nps[c] * Kps[c];
            prep_w<<<(tot + 255) / 256, 256, 0, stream>>>(W, wh, wl, Ks[c], Ns[c], Kps[c], Nps[c]);
        }
    }

    for (int br = 0; br < 2; ++br) {
        const float* x   = br == 0 ? x1 : x2;
        const int*   ei  = br == 0 ? ei1 : ei2;
        const int*   src = ei;
        const int*   dst = ei + E;
        int base = 7 + br * 10;
        const float* bias_c[3] = { (const float*)d_in[base + 1], (const float*)d_in[base + 3],
                                   (const float*)d_in[base + 5] };
        const float* bfc1w = (const float*)d_in[base + 6];
        const float* bfc1b = (const float*)d_in[base + 7];
        const float* bfc2w = (const float*)d_in[base + 8];
        const float* bfc2b = (const float*)d_in[base + 9];

        // ---- CSR build ----
        hipMemsetAsync(cnt, 0, N_NODES * sizeof(int), stream);
        count_deg<<<EB, 256, 0, stream>>>(dst, cnt, E);
        make_dinv<<<NB, 256, 0, stream>>>(cnt, dinv, N_NODES);
        scan_rowptr<<<1, 1024, 0, stream>>>(cnt, rowp);
        hipMemsetAsync(cnt, 0, N_NODES * sizeof(int), stream);   // cnt reused as cursor
        fill_csr<<<EB, 256, 0, stream>>>(src, dst, rowp, cnt, csrs, E);

        // conv inputs/outputs: x->y1@R1 -> y2@R2 -> y3@R1
        const float* cin[3] = { x, R1, R2 };
        float*       cout[3] = { R1, R2, R1 };
        for (int c = 0; c < 3; ++c) {
            int Kp = Kps[c], Np = Nps[c];
            int total = N_NODES * (Kp >> 1);
            gather_split<<<(total + 255) / 256, 256, 0, stream>>>(
                cin[c], rowp, csrs, dinv, Ahb, Alb, Ks[c], Kp);
            unsigned short* wh = wt + br * WT_BRANCH + wtoff[c];
            unsigned short* wl = wh + Np * Kp;
            dim3 grid(Np / 128, N_NODES / 128);
            gemm_mfma_split<<<grid, 256, 0, stream>>>(Ahb, Alb, wh, wl, bias_c[c],
                                                      cout[c], Ns[c], Kp);
        }

        // ---- pool + branch MLP ----
        float* pooled = R2;                       // y2 dead
        float* fc_out = (float*)((char*)R2 + 2097152);
        pool_max<<<N_GRAPHS, 256, 0, stream>>>(R1, pooled, FD * 4);
        fc_launch(pooled, bfc1w, bfc1b, fc_out, N_GRAPHS, 1024, FD * 4, FD * 4, 1024, 1, stream);
        fc_launch(fc_out, bfc2w, bfc2b, xc + br * 64, N_GRAPHS, 64, 1024, 1024, 256, 0, stream);
    }

    // xt + head
    fc_launch(target, xt_w, xt_b, xc + 128, N_GRAPHS, 128, 1000, 1000, 256, 0, stream);
    fc_launch(xc,  fc1_w, fc1_b, xc1, N_GRAPHS, 128, 256, 256, 128, 1, stream);
    fc_launch(xc1, fc2_w, fc2_b, xc2, N_GRAPHS, 32, 128, 128, 32, 1, stream);
    fc_launch(xc2, out_w, out_b, (float*)d_out, N_GRAPHS, 1, 32, 32, 1, 0, stream);
}

// Round 6
// 936.819 us; speedup vs baseline: 6.1017x; 1.1729x over previous
//
#include <hip/hip_runtime.h>
#include <hip/hip_bf16.h>
#include <math.h>

#define N_NODES 65536
#define N_EDGES 524288
#define N_GRAPHS 1024
#define NPG 64
#define FD 78
#define RPS 65600   // row_ptr stride (ints) per branch

typedef __attribute__((ext_vector_type(8))) short bf16x8;
typedef __attribute__((ext_vector_type(4))) float f32x4;

__device__ __forceinline__ unsigned short f2bf(float v) {
    unsigned int u = __float_as_uint(v);
    unsigned int r = (u + 0x7FFFu + ((u >> 16) & 1u)) >> 16;
    return (unsigned short)r;
}
__device__ __forceinline__ float bf2f(unsigned short h) {
    return __uint_as_float(((unsigned int)h) << 16);
}

// ---------------- split-bf16 MFMA GEMM ----------------
// C[M(=65536), ldc] = A[M,Kp] @ Wt[Np,Kp]^T (+bias, +relu), pad cols [N,ldc) zeroed.
// 3-pass split: Ah*Wh + Ah*Wl + Al*Wh. 256 thr = 4 waves (2x2), tile 128x128.
__global__ __launch_bounds__(256) void gemm_mfma_split(
    const unsigned short* __restrict__ Ah, const unsigned short* __restrict__ Al,
    const unsigned short* __restrict__ Wh, const unsigned short* __restrict__ Wl,
    const float* __restrict__ bias, float* __restrict__ C,
    int N, int Kp, int ldc)
{
    __shared__ __align__(16) unsigned short sAh[128][40];
    __shared__ __align__(16) unsigned short sAl[128][40];
    __shared__ __align__(16) unsigned short sBh[128][40];
    __shared__ __align__(16) unsigned short sBl[128][40];

    int tid = threadIdx.x;
    int bm = blockIdx.y << 7;
    int bn = blockIdx.x << 7;
    int lane = tid & 63;
    int wid = tid >> 6;
    int wr = wid >> 1, wc = wid & 1;
    int cr = lane & 15;
    int kg = lane >> 4;

    f32x4 acc[4][4] = {};

    for (int k0 = 0; k0 < Kp; k0 += 32) {
        #pragma unroll
        for (int s = tid; s < 512; s += 256) {
            int r = s >> 2, seg = s & 3;
            *(uint4*)&sAh[r][seg * 8] =
                *(const uint4*)(Ah + (size_t)(bm + r) * Kp + k0 + seg * 8);
        }
        #pragma unroll
        for (int s = tid; s < 512; s += 256) {
            int r = s >> 2, seg = s & 3;
            *(uint4*)&sAl[r][seg * 8] =
                *(const uint4*)(Al + (size_t)(bm + r) * Kp + k0 + seg * 8);
        }
        #pragma unroll
        for (int s = tid; s < 512; s += 256) {
            int r = s >> 2, seg = s & 3;
            *(uint4*)&sBh[r][seg * 8] =
                *(const uint4*)(Wh + (size_t)(bn + r) * Kp + k0 + seg * 8);
        }
        #pragma unroll
        for (int s = tid; s < 512; s += 256) {
            int r = s >> 2, seg = s & 3;
            *(uint4*)&sBl[r][seg * 8] =
                *(const uint4*)(Wl + (size_t)(bn + r) * Kp + k0 + seg * 8);
        }
        __syncthreads();

        bf16x8 bH[4], bL[4];
        #pragma unroll
        for (int nf = 0; nf < 4; ++nf) {
            bH[nf] = *(const bf16x8*)&sBh[wc * 64 + nf * 16 + cr][kg * 8];
            bL[nf] = *(const bf16x8*)&sBl[wc * 64 + nf * 16 + cr][kg * 8];
        }
        #pragma unroll
        for (int mf = 0; mf < 4; ++mf) {
            bf16x8 aH = *(const bf16x8*)&sAh[wr * 64 + mf * 16 + cr][kg * 8];
            bf16x8 aL = *(const bf16x8*)&sAl[wr * 64 + mf * 16 + cr][kg * 8];
            #pragma unroll
            for (int nf = 0; nf < 4; ++nf) {
                acc[mf][nf] = __builtin_amdgcn_mfma_f32_16x16x32_bf16(aH, bH[nf], acc[mf][nf], 0, 0, 0);
                acc[mf][nf] = __builtin_amdgcn_mfma_f32_16x16x32_bf16(aH, bL[nf], acc[mf][nf], 0, 0, 0);
                acc[mf][nf] = __builtin_amdgcn_mfma_f32_16x16x32_bf16(aL, bH[nf], acc[mf][nf], 0, 0, 0);
            }
        }
        __syncthreads();
    }

    // epilogue: C/D layout col=lane&15, row=(lane>>4)*4+reg; pad cols [N,ldc)=0
    #pragma unroll
    for (int mf = 0; mf < 4; ++mf) {
        int rowbase = bm + wr * 64 + mf * 16 + kg * 4;
        #pragma unroll
        for (int nf = 0; nf < 4; ++nf) {
            int col = bn + wc * 64 + nf * 16 + cr;
            if (col < ldc) {
                float bv = (col < N) ? bias[col] : 0.f;
                f32x4 v = acc[mf][nf];
                #pragma unroll
                for (int j = 0; j < 4; ++j) {
                    float o = (col < N) ? fmaxf(v[j] + bv, 0.f) : 0.f;
                    C[(size_t)(rowbase + j) * ldc + col] = o;
                }
            }
        }
    }
}

// ---------------- weight prep: W[K,N] f32 -> Wt hi/lo bf16 [Np][Kp] ----------------
__global__ void prep_w(const float* __restrict__ W, unsigned short* __restrict__ Wh,
                       unsigned short* __restrict__ Wl, int K, int N, int Kp, int Np) {
    int t = blockIdx.x * blockDim.x + threadIdx.x;
    if (t >= Np * Kp) return;
    int n = t / Kp, k = t - n * Kp;
    float v = (n < N && k < K) ? W[(size_t)k * N + n] : 0.f;
    unsigned short h = f2bf(v);
    float lo = v - bf2f(h);
    Wh[t] = h;
    Wl[t] = f2bf(lo);
}

// ---------------- small-M FC: one wave = one row x 64 consecutive cols ----------------
__global__ __launch_bounds__(256) void fc_row(
    const float* __restrict__ A, const float* __restrict__ B,
    const float* __restrict__ bias, float* __restrict__ C,
    int M, int N, int K, int lda, int ldc, int relu)
{
    int nchunks = (N + 63) >> 6;
    int bid = blockIdx.x;
    int nc = bid % nchunks;
    int m = ((bid / nchunks) << 2) + (threadIdx.x >> 6);
    int lane = threadIdx.x & 63;
    if (m >= M) return;
    int n = (nc << 6) + lane;
    int nclamp = n < N ? n : N - 1;
    const float* __restrict__ a = A + (size_t)m * lda;
    const float* __restrict__ bp = B + nclamp;
    float acc = 0.f;
    int kk = 0;
    #pragma unroll 4
    for (; kk + 4 <= K; kk += 4) {
        float a0 = a[kk + 0], a1 = a[kk + 1], a2 = a[kk + 2], a3 = a[kk + 3];
        float b0 = bp[(size_t)(kk + 0) * N];
        float b1 = bp[(size_t)(kk + 1) * N];
        float b2 = bp[(size_t)(kk + 2) * N];
        float b3 = bp[(size_t)(kk + 3) * N];
        acc = fmaf(a0, b0, acc);
        acc = fmaf(a1, b1, acc);
        acc = fmaf(a2, b2, acc);
        acc = fmaf(a3, b3, acc);
    }
    for (; kk < K; ++kk)
        acc = fmaf(a[kk], bp[(size_t)kk * N], acc);
    if (n < N) {
        float v = acc + bias[n];
        if (relu) v = fmaxf(v, 0.f);
        C[(size_t)m * ldc + n] = v;
    }
}

// ---------------- graph helper kernels (both branches fused) ----------------
__global__ void count_deg2(const int* __restrict__ d1, const int* __restrict__ d2,
                           int* __restrict__ cnt, int E) {
    int t = blockIdx.x * blockDim.x + threadIdx.x;
    if (t >= 2 * E) return;
    int b = t >= E;
    int e = t - b * E;
    const int* d = b ? d2 : d1;
    atomicAdd(&cnt[b * N_NODES + d[e]], 1);
}

__global__ void make_dinv2(const int* __restrict__ cnt, float* __restrict__ dinv) {
    int t = blockIdx.x * blockDim.x + threadIdx.x;
    if (t < 2 * N_NODES) dinv[t] = rsqrtf((float)cnt[t] + 1.0f);
}

// grid.x = 2 (one block per branch)
__global__ __launch_bounds__(1024) void scan_rowptr(const int* __restrict__ cntB,
                                                    int* __restrict__ rowpB) {
    __shared__ int sums[1024];
    const int* cnt = cntB + blockIdx.x * N_NODES;
    int* row_ptr = rowpB + blockIdx.x * RPS;
    int t = threadIdx.x;
    int base = t * 64;
    int s = 0;
    #pragma unroll 4
    for (int i = 0; i < 64; ++i) s += cnt[base + i];
    sums[t] = s;
    __syncthreads();
    for (int off = 1; off < 1024; off <<= 1) {
        int v = sums[t];
        int add = (t >= off) ? sums[t - off] : 0;
        __syncthreads();
        sums[t] = v + add;
        __syncthreads();
    }
    int run = (t == 0) ? 0 : sums[t - 1];
    for (int i = 0; i < 64; ++i) {
        row_ptr[base + i] = run;
        run += cnt[base + i];
    }
    if (t == 1023) row_ptr[N_NODES] = run;
}

__global__ void fill_csr2(const int* __restrict__ s1, const int* __restrict__ d1,
                          const int* __restrict__ s2, const int* __restrict__ d2,
                          const int* __restrict__ rowpB, int* __restrict__ cur,
                          int* __restrict__ csrsB, int E) {
    int t = blockIdx.x * blockDim.x + threadIdx.x;
    if (t >= 2 * E) return;
    int b = t >= E;
    int e = t - b * E;
    const int* sp = b ? s2 : s1;
    const int* dp = b ? d2 : d1;
    int d = dp[e];
    int pos = rowpB[b * RPS + d] + atomicAdd(&cur[b * N_NODES + d], 1);
    csrsB[b * E + pos] = sp[e];
}

// pad-repack: x[N,F] -> xp[N,S] (zero pad cols F..S)
__global__ void repack_pad(const float* __restrict__ x, float* __restrict__ xp,
                           int F, int S) {
    int t = blockIdx.x * blockDim.x + threadIdx.x;
    int total = N_NODES * S;
    if (t >= total) return;
    int i = t / S, c = t - i * S;
    xp[t] = (c < F) ? x[(size_t)i * F + c] : 0.f;
}

// gather + normalize + split, 8 features per thread, float4 loads, edge loop x2
// x rows have stride S (padded, zero-filled); A padded to Kp (groups f>=S zeroed)
__global__ __launch_bounds__(256) void gather8(
    const float* __restrict__ x, const int* __restrict__ rowp,
    const int* __restrict__ csrs, const float* __restrict__ dinv,
    unsigned short* __restrict__ Ah, unsigned short* __restrict__ Al,
    int S, int Kp)
{
    int Kp8 = Kp >> 3;
    int t = blockIdx.x * blockDim.x + threadIdx.x;
    int total = N_NODES * Kp8;
    if (t >= total) return;
    int i = t / Kp8;
    int g = t - i * Kp8;
    int f = g << 3;
    size_t ob = (size_t)i * Kp + f;
    if (f >= S) {
        bf16x8 z = {};
        *(bf16x8*)&Ah[ob] = z;
        *(bf16x8*)&Al[ob] = z;
        return;
    }
    float di = dinv[i];
    const float* xr = x + (size_t)i * S + f;
    f32x4 s0 = *(const f32x4*)xr;
    f32x4 s1 = *(const f32x4*)(xr + 4);
    float w = di * di;
    s0 *= w;
    s1 *= w;
    int p0 = rowp[i], p1 = rowp[i + 1];
    int p = p0;
    for (; p + 2 <= p1; p += 2) {
        int sa = csrs[p], sb = csrs[p + 1];
        float ca = dinv[sa] * di, cb = dinv[sb] * di;
        const float* ra = x + (size_t)sa * S + f;
        const float* rb = x + (size_t)sb * S + f;
        f32x4 a0 = *(const f32x4*)ra;
        f32x4 a1 = *(const f32x4*)(ra + 4);
        f32x4 b0 = *(const f32x4*)rb;
        f32x4 b1 = *(const f32x4*)(rb + 4);
        s0 += ca * a0 + cb * b0;
        s1 += ca * a1 + cb * b1;
    }
    if (p < p1) {
        int sa = csrs[p];
        float ca = dinv[sa] * di;
        const float* ra = x + (size_t)sa * S + f;
        s0 += ca * *(const f32x4*)ra;
        s1 += ca * *(const f32x4*)(ra + 4);
    }
    bf16x8 hh, ll;
    #pragma unroll
    for (int j = 0; j < 4; ++j) {
        unsigned short h0 = f2bf(s0[j]);
        hh[j] = (short)h0;
        ll[j] = (short)f2bf(s0[j] - bf2f(h0));
        unsigned short h1 = f2bf(s1[j]);
        hh[4 + j] = (short)h1;
        ll[4 + j] = (short)f2bf(s1[j] - bf2f(h1));
    }
    *(bf16x8*)&Ah[ob] = hh;
    *(bf16x8*)&Al[ob] = ll;
}

// global max pool: 64 contiguous nodes per graph
__global__ void pool_max(const float* __restrict__ y, float* __restrict__ out, int F) {
    int g = blockIdx.x;
    for (int f = threadIdx.x; f < F; f += blockDim.x) {
        float m = -INFINITY;
        const float* p = y + (size_t)g * NPG * F + f;
        #pragma unroll 4
        for (int n = 0; n < NPG; ++n) m = fmaxf(m, p[(size_t)n * F]);
        out[(size_t)g * F + f] = m;
    }
}

// ---------------- host side ----------------
static inline void fc_launch(const float* A, const float* B, const float* bias, float* C,
                             int M, int N, int K, int lda, int ldc, int relu, hipStream_t s) {
    int nchunks = (N + 63) / 64;
    int mblocks = (M + 3) / 4;
    fc_row<<<nchunks * mblocks, 256, 0, s>>>(A, B, bias, C, M, N, K, lda, ldc, relu);
}

extern "C" void kernel_launch(void* const* d_in, const int* in_sizes, int n_in,
                              void* d_out, int out_size, void* d_ws, size_t ws_size,
                              hipStream_t stream) {
    (void)in_sizes; (void)n_in; (void)out_size; (void)ws_size;

    const float* x1     = (const float*)d_in[0];
    const int*   ei1    = (const int*)d_in[1];
    const float* x2     = (const float*)d_in[3];
    const int*   ei2    = (const int*)d_in[4];
    const float* target = (const float*)d_in[6];

    const float* xt_w  = (const float*)d_in[27];
    const float* xt_b  = (const float*)d_in[28];
    const float* fc1_w = (const float*)d_in[29];
    const float* fc1_b = (const float*)d_in[30];
    const float* fc2_w = (const float*)d_in[31];
    const float* fc2_b = (const float*)d_in[32];
    const float* out_w = (const float*)d_in[33];
    const float* out_b = (const float*)d_in[34];

    char* ws = (char*)d_ws;
    unsigned short* Ahb = (unsigned short*)(ws + 0);           // 20,971,520
    unsigned short* Alb = (unsigned short*)(ws + 20971520);    // 20,971,520
    float* Y3   = (float*)(ws + 41943040);    // 81,788,928 (y3; xpad/y1 alias at base, 21.0MB)
    float* Y2   = (float*)(ws + 123731968);   // 41,943,040 (y2; pooled/fc_out alias after death)
    int*   csrsB = (int*) (ws + 165675008);   // 2 x 2,097,152
    int*   rowpB = (int*) (ws + 169869312);   // 2 x 262,400
    int*   cntB  = (int*) (ws + 170394112);   // 2 x 262,144 (also cursors)
    float* dinvB = (float*)(ws + 170918400);  // 2 x 262,144
    float* xc   = (float*)(ws + 171442688);   // 1,048,576
    float* xc1  = (float*)(ws + 172491264);   // 524,288
    float* xc2  = (float*)(ws + 173015552);   // 131,072
    unsigned short* wt = (unsigned short*)(ws + 173146624);   // 786,432

    float* xpad = Y3;                         // [65536 x 80], aliases y1, then y3
    float* y1   = Y3;
    float* y2   = Y2;
    float* y3   = Y3;

    const int E = N_EDGES;

    // conv geometry
    const int Ks[3]  = { FD, FD, FD * 2 };        // 78, 78, 156
    const int Ns[3]  = { FD, FD * 2, FD * 4 };    // 78, 156, 312
    const int Kps[3] = { 96, 96, 160 };
    const int Nps[3] = { 128, 256, 384 };
    const int Ss[3]  = { 80, 80, 160 };           // input row strides
    const int Ldc[3] = { 80, 160, 312 };          // output row strides
    const int wtoff[3] = { 0, 24576, 73728 };
    const int WT_BRANCH = 196608;

    // ---- weight prep (all convs, both branches) ----
    for (int br = 0; br < 2; ++br) {
        int base = 7 + br * 10;
        for (int c = 0; c < 3; ++c) {
            const float* W = (const float*)d_in[base + 2 * c];
            unsigned short* wh = wt + br * WT_BRANCH + wtoff[c];
            unsigned short* wl = wh + Nps[c] * Kps[c];
            int tot = Nps[c] * Kps[c];
            prep_w<<<(tot + 255) / 256, 256, 0, stream>>>(W, wh, wl, Ks[c], Ns[c], Kps[c], Nps[c]);
        }
    }

    // ---- CSR build, both branches fused ----
    const int* src1 = ei1, *dst1 = ei1 + E;
    const int* src2 = ei2, *dst2 = ei2 + E;
    hipMemsetAsync(cntB, 0, 2 * N_NODES * sizeof(int), stream);
    count_deg2<<<(2 * E + 255) / 256, 256, 0, stream>>>(dst1, dst2, cntB, E);
    make_dinv2<<<(2 * N_NODES + 255) / 256, 256, 0, stream>>>(cntB, dinvB);
    scan_rowptr<<<2, 1024, 0, stream>>>(cntB, rowpB);
    hipMemsetAsync(cntB, 0, 2 * N_NODES * sizeof(int), stream);
    fill_csr2<<<(2 * E + 255) / 256, 256, 0, stream>>>(src1, dst1, src2, dst2,
                                                       rowpB, cntB, csrsB, E);

    for (int br = 0; br < 2; ++br) {
        const float* x = br == 0 ? x1 : x2;
        const int* rowp = rowpB + br * RPS;
        const int* csr  = csrsB + br * E;
        const float* dv = dinvB + br * N_NODES;
        int base = 7 + br * 10;
        const float* bias_c[3] = { (const float*)d_in[base + 1], (const float*)d_in[base + 3],
                                   (const float*)d_in[base + 5] };
        const float* bfc1w = (const float*)d_in[base + 6];
        const float* bfc1b = (const float*)d_in[base + 7];
        const float* bfc2w = (const float*)d_in[base + 8];
        const float* bfc2b = (const float*)d_in[base + 9];

        // pad-repack raw x to stride 80
        repack_pad<<<(N_NODES * 80 + 255) / 256, 256, 0, stream>>>(x, xpad, FD, 80);

        const float* cin[3]  = { xpad, y1, y2 };
        float*       cout[3] = { y1, y2, y3 };
        for (int c = 0; c < 3; ++c) {
            int Kp = Kps[c], Np = Nps[c], S = Ss[c];
            int total = N_NODES * (Kp >> 3);
            gather8<<<(total + 255) / 256, 256, 0, stream>>>(
                cin[c], rowp, csr, dv, Ahb, Alb, S, Kp);
            unsigned short* wh = wt + br * WT_BRANCH + wtoff[c];
            unsigned short* wl = wh + Np * Kp;
            dim3 grid(Np / 128, N_NODES / 128);
            gemm_mfma_split<<<grid, 256, 0, stream>>>(Ahb, Alb, wh, wl, bias_c[c],
                                                      cout[c], Ns[c], Kp, Ldc[c]);
        }

        // ---- pool + branch MLP (y2 dead -> reuse) ----
        float* pooled = Y2;
        float* fc_out = (float*)((char*)Y2 + 2097152);
        pool_max<<<N_GRAPHS, 256, 0, stream>>>(y3, pooled, FD * 4);
        fc_launch(pooled, bfc1w, bfc1b, fc_out, N_GRAPHS, 1024, FD * 4, FD * 4, 1024, 1, stream);
        fc_launch(fc_out, bfc2w, bfc2b, xc + br * 64, N_GRAPHS, 64, 1024, 1024, 256, 0, stream);
    }

    // xt + head
    fc_launch(target, xt_w, xt_b, xc + 128, N_GRAPHS, 128, 1000, 1000, 256, 0, stream);
    fc_launch(xc,  fc1_w, fc1_b, xc1, N_GRAPHS, 128, 256, 256, 128, 1, stream);
    fc_launch(xc1, fc2_w, fc2_b, xc2, N_GRAPHS, 32, 128, 128, 32, 1, stream);
    fc_launch(xc2, out_w, out_b, (float*)d_out, N_GRAPHS, 1, 32, 32, 1, 0, stream);
}